// Round 1
// baseline (4336.234 us; speedup 1.0000x reference)
//
#include <hip/hip_runtime.h>

#define BM 64
#define BN 64
#define BKK 16

// ---------------- degree / scale kernels ----------------
__global__ __launch_bounds__(256)
void count_deg_kernel(const int* __restrict__ s0, const int* __restrict__ d0,
                      const int* __restrict__ s1, const int* __restrict__ d1,
                      const int* __restrict__ s2, const int* __restrict__ d2,
                      int* __restrict__ deg, int E, int Nn)
{
    int z = blockIdx.z;
    const int* sp = (z == 0) ? s0 : ((z == 1) ? s1 : s2);
    const int* dp = (z == 0) ? d0 : ((z == 1) ? d1 : d2);
    int e = blockIdx.x * blockDim.x + threadIdx.x;
    if (e >= E) return;
    atomicAdd(&deg[z * Nn + sp[e]], 1);        // out-degree (src) for type z
    atomicAdd(&deg[(3 + z) * Nn + dp[e]], 1);  // in-degree (dst)
}

__global__ __launch_bounds__(256)
void make_scales_kernel(const int* __restrict__ deg, float* __restrict__ scales, int total)
{
    int i = blockIdx.x * blockDim.x + threadIdx.x;
    if (i >= total) return;
    int dv = deg[i];
    if (dv < 1) dv = 1;
    scales[i] = rsqrtf((float)dv);
}

// ---------------- fp32 tiled GEMM with per-row scale epilogue ----------------
// C[z][r][c] = s_out[z][r] * sum_k A[r][k] * Bz[k][c]
__global__ __launch_bounds__(256)
void gemm_scaled_kernel(const float* __restrict__ A,
                        const float* __restrict__ B0, const float* __restrict__ B1,
                        const float* __restrict__ B2,
                        const float* __restrict__ scales,  // s_out[t*M + r]
                        float* __restrict__ Cbase,
                        int M, int K, int Ncols)
{
    const int z = blockIdx.z;
    const float* B = (z == 0) ? B0 : ((z == 1) ? B1 : B2);
    const float* s = scales + (size_t)z * M;
    float* C = Cbase + (size_t)z * M * Ncols;

    __shared__ float As[BKK][BM + 4];  // A tile transposed, padded (16B-aligned rows)
    __shared__ float Bs[BKK][BN];

    const int tid = threadIdx.x;
    const int tx = tid & 15;   // 16 col groups
    const int ty = tid >> 4;   // 16 row groups
    const int row0 = blockIdx.y * BM;
    const int col0 = blockIdx.x * BN;

    // A load mapping: 256 threads load 64x16 tile, float4 along K
    const int ar  = tid >> 2;        // 0..63
    const int ac4 = (tid & 3) * 4;   // 0,4,8,12
    // B load mapping: 16x64 tile, float4 along N
    const int br  = tid >> 4;        // 0..15
    const int bc4 = (tid & 15) * 4;  // 0..60

    float acc[4][4] = {};

    for (int k0 = 0; k0 < K; k0 += BKK) {
        // ---- A tile ----
        float4 av = make_float4(0.f, 0.f, 0.f, 0.f);
        const int arow = row0 + ar;
        const int kc = k0 + ac4;
        if (arow < M) {
            if (kc + 3 < K) {
                av = *reinterpret_cast<const float4*>(A + (size_t)arow * K + kc);
            } else {
                float t0 = (kc + 0 < K) ? A[(size_t)arow * K + kc + 0] : 0.f;
                float t1 = (kc + 1 < K) ? A[(size_t)arow * K + kc + 1] : 0.f;
                float t2 = (kc + 2 < K) ? A[(size_t)arow * K + kc + 2] : 0.f;
                float t3 = (kc + 3 < K) ? A[(size_t)arow * K + kc + 3] : 0.f;
                av = make_float4(t0, t1, t2, t3);
            }
        }
        As[ac4 + 0][ar] = av.x;
        As[ac4 + 1][ar] = av.y;
        As[ac4 + 2][ar] = av.z;
        As[ac4 + 3][ar] = av.w;

        // ---- B tile ----
        float4 bv = make_float4(0.f, 0.f, 0.f, 0.f);
        const int brow = k0 + br;
        if (brow < K) {
            bv = *reinterpret_cast<const float4*>(B + (size_t)brow * Ncols + col0 + bc4);
        }
        *reinterpret_cast<float4*>(&Bs[br][bc4]) = bv;

        __syncthreads();

        #pragma unroll
        for (int k = 0; k < BKK; ++k) {
            float4 a4 = *reinterpret_cast<const float4*>(&As[k][ty * 4]);
            float4 b4 = *reinterpret_cast<const float4*>(&Bs[k][tx * 4]);
            float aa[4] = {a4.x, a4.y, a4.z, a4.w};
            float bb[4] = {b4.x, b4.y, b4.z, b4.w};
            #pragma unroll
            for (int i = 0; i < 4; ++i)
                #pragma unroll
                for (int j = 0; j < 4; ++j)
                    acc[i][j] = fmaf(aa[i], bb[j], acc[i][j]);
        }
        __syncthreads();
    }

    #pragma unroll
    for (int i = 0; i < 4; ++i) {
        const int r = row0 + ty * 4 + i;
        if (r < M) {
            const float sc = s[r];
            float4 o = make_float4(acc[i][0] * sc, acc[i][1] * sc,
                                   acc[i][2] * sc, acc[i][3] * sc);
            *reinterpret_cast<float4*>(C + (size_t)r * Ncols + col0 + tx * 4) = o;
        }
    }
}

// ---------------- scatter-aggregate (wave per edge) ----------------
template <int F, int VEC>
__global__ __launch_bounds__(256)
void scatter_kernel(const float* __restrict__ pre,  // [3][Nn][F]
                    float* __restrict__ out,        // [3][Nn][F], pre-zeroed
                    const int* __restrict__ s0, const int* __restrict__ d0,
                    const int* __restrict__ s1, const int* __restrict__ d1,
                    const int* __restrict__ s2, const int* __restrict__ d2,
                    int E, int Nn)
{
    const int z = blockIdx.z;
    const int* sp = (z == 0) ? s0 : ((z == 1) ? s1 : s2);
    const int* dp = (z == 0) ? d0 : ((z == 1) ? d1 : d2);
    const float* P = pre + (size_t)z * Nn * F;
    float* O = out + (size_t)z * Nn * F;

    const int wave = blockIdx.x * 4 + (threadIdx.x >> 6);
    const int lane = threadIdx.x & 63;
    if (wave >= E) return;
    const int sn = sp[wave];
    const int dn = dp[wave];
    const float* srcp = P + (size_t)sn * F + lane * VEC;
    float* dstp = O + (size_t)dn * F + lane * VEC;
    if constexpr (VEC == 4) {
        float4 v = *reinterpret_cast<const float4*>(srcp);
        atomicAdd(&dstp[0], v.x);
        atomicAdd(&dstp[1], v.y);
        atomicAdd(&dstp[2], v.z);
        atomicAdd(&dstp[3], v.w);
    } else {
        float2 v = *reinterpret_cast<const float2*>(srcp);
        atomicAdd(&dstp[0], v.x);
        atomicAdd(&dstp[1], v.y);
    }
}

// ---------------- fused dual-attention (wave per node) ----------------
// ht[t] = raw[t][n]*s_in[t][n] + b_t ; mean = avg_t ht
// sc_t = ht[t].a[:F] + mean.a[F:] ; LeakyReLU(0.2) ; softmax over t
// out = sum_t attn_t * ht[t]  (optionally LeakyReLU(0.01))
template <int F, int VEC, bool LEAKY01>
__global__ __launch_bounds__(256)
void attn_kernel(const float* __restrict__ raw,
                 const float* __restrict__ sin_,   // s_in[t*Nn + n]
                 const float* __restrict__ bb0, const float* __restrict__ bb1,
                 const float* __restrict__ bb2,
                 const float* __restrict__ a,      // [2F]
                 float* __restrict__ out, int Nn)
{
    const int wave = blockIdx.x * 4 + (threadIdx.x >> 6);
    const int lane = threadIdx.x & 63;
    if (wave >= Nn) return;
    const int n = wave;
    const size_t NF = (size_t)Nn * F;
    const int fo = lane * VEC;

    float ht[3][VEC];
    float mean[VEC];
    #pragma unroll
    for (int v = 0; v < VEC; ++v) mean[v] = 0.f;

    const float* bptr[3] = {bb0, bb1, bb2};
    #pragma unroll
    for (int t = 0; t < 3; ++t) {
        const float si = sin_[t * Nn + n];
        const float* rp = raw + t * NF + (size_t)n * F + fo;
        const float* bp = bptr[t] + fo;
        #pragma unroll
        for (int v = 0; v < VEC; ++v) {
            const float xv = fmaf(rp[v], si, bp[v]);
            ht[t][v] = xv;
            mean[v] += xv;
        }
    }
    #pragma unroll
    for (int v = 0; v < VEC; ++v) mean[v] *= (1.0f / 3.0f);

    float p0 = 0.f, p1 = 0.f, p2 = 0.f, p3 = 0.f;
    #pragma unroll
    for (int v = 0; v < VEC; ++v) {
        const float aA = a[fo + v];
        const float aB = a[F + fo + v];
        p0 = fmaf(ht[0][v], aA, p0);
        p1 = fmaf(ht[1][v], aA, p1);
        p2 = fmaf(ht[2][v], aA, p2);
        p3 = fmaf(mean[v], aB, p3);
    }
    #pragma unroll
    for (int off = 1; off < 64; off <<= 1) {
        p0 += __shfl_xor(p0, off);
        p1 += __shfl_xor(p1, off);
        p2 += __shfl_xor(p2, off);
        p3 += __shfl_xor(p3, off);
    }
    float sc0 = p0 + p3, sc1 = p1 + p3, sc2 = p2 + p3;
    sc0 = sc0 > 0.f ? sc0 : 0.2f * sc0;
    sc1 = sc1 > 0.f ? sc1 : 0.2f * sc1;
    sc2 = sc2 > 0.f ? sc2 : 0.2f * sc2;
    const float m = fmaxf(sc0, fmaxf(sc1, sc2));
    const float e0 = __expf(sc0 - m);
    const float e1 = __expf(sc1 - m);
    const float e2 = __expf(sc2 - m);
    const float inv = 1.0f / (e0 + e1 + e2);
    const float at0 = e0 * inv, at1 = e1 * inv, at2 = e2 * inv;

    float* op = out + (size_t)n * F + fo;
    #pragma unroll
    for (int v = 0; v < VEC; ++v) {
        float o = at0 * ht[0][v] + at1 * ht[1][v] + at2 * ht[2][v];
        if constexpr (LEAKY01) o = o > 0.f ? o : 0.01f * o;
        op[v] = o;
    }
}

// ---------------- fc head (wave per node) ----------------
__global__ __launch_bounds__(256)
void fc_kernel(const float* __restrict__ h,   // [Nn][128]
               const float* __restrict__ w,   // [128][10]
               const float* __restrict__ b,   // [10]
               float* __restrict__ logits, int Nn)
{
    const int wave = blockIdx.x * 4 + (threadIdx.x >> 6);
    const int lane = threadIdx.x & 63;
    if (wave >= Nn) return;
    const float hA = h[(size_t)wave * 128 + lane];
    const float hB = h[(size_t)wave * 128 + 64 + lane];
    float acc[10];
    #pragma unroll
    for (int c = 0; c < 10; ++c)
        acc[c] = fmaf(hA, w[lane * 10 + c], hB * w[(64 + lane) * 10 + c]);
    #pragma unroll
    for (int off = 1; off < 64; off <<= 1) {
        #pragma unroll
        for (int c = 0; c < 10; ++c) acc[c] += __shfl_xor(acc[c], off);
    }
    if (lane == 0) {
        #pragma unroll
        for (int c = 0; c < 10; ++c) logits[(size_t)wave * 10 + c] = acc[c] + b[c];
    }
}

extern "C" void kernel_launch(void* const* d_in, const int* in_sizes, int n_in,
                              void* d_out, int out_size, void* d_ws, size_t ws_size,
                              hipStream_t stream)
{
    const float* x = (const float*)d_in[0];
    const int* src[3] = {(const int*)d_in[1], (const int*)d_in[3], (const int*)d_in[5]};
    const int* dst[3] = {(const int*)d_in[2], (const int*)d_in[4], (const int*)d_in[6]};
    const float* W0[3] = {(const float*)d_in[7],  (const float*)d_in[11], (const float*)d_in[15]};
    const float* b0[3] = {(const float*)d_in[8],  (const float*)d_in[12], (const float*)d_in[16]};
    const float* W1[3] = {(const float*)d_in[9],  (const float*)d_in[13], (const float*)d_in[17]};
    const float* b1[3] = {(const float*)d_in[10], (const float*)d_in[14], (const float*)d_in[18]};
    const float* a0  = (const float*)d_in[19];
    const float* a1  = (const float*)d_in[20];
    const float* fcw = (const float*)d_in[21];
    const float* fcb = (const float*)d_in[22];

    const int Nn = in_sizes[0] / 300;  // 20000
    const int E  = in_sizes[1];        // 320000

    // workspace layout (floats)
    float* ws = (float*)d_ws;
    int*   deg    = (int*)ws;                         // 6N ints
    float* scales = ws + 6 * (size_t)Nn;              // 6N: s_out[3][N], s_in[3][N]
    float* buf1   = scales + 6 * (size_t)Nn;          // 3*N*256 (pre-agg, scaled)
    float* buf2   = buf1 + 3 * (size_t)Nn * 256;      // 3*N*256 (aggregated, raw)
    float* h1     = buf2 + 3 * (size_t)Nn * 256;      // N*256
    float* outH   = (float*)d_out;                    // N*128
    float* logits = outH + (size_t)Nn * 128;          // N*10

    hipMemsetAsync(deg, 0, 6 * (size_t)Nn * sizeof(int), stream);
    hipMemsetAsync(buf2, 0, 3 * (size_t)Nn * 256 * sizeof(float), stream);

    {
        dim3 g((E + 255) / 256, 1, 3);
        count_deg_kernel<<<g, 256, 0, stream>>>(src[0], dst[0], src[1], dst[1],
                                                src[2], dst[2], deg, E, Nn);
    }
    make_scales_kernel<<<(6 * Nn + 255) / 256, 256, 0, stream>>>(deg, scales, 6 * Nn);

    // ---- layer 1 ----
    {
        dim3 g(256 / BN, (Nn + BM - 1) / BM, 3);
        gemm_scaled_kernel<<<g, 256, 0, stream>>>(x, W0[0], W0[1], W0[2],
                                                  scales, buf1, Nn, 300, 256);
    }
    {
        dim3 g((E + 3) / 4, 1, 3);
        scatter_kernel<256, 4><<<g, 256, 0, stream>>>(buf1, buf2,
            src[0], dst[0], src[1], dst[1], src[2], dst[2], E, Nn);
    }
    attn_kernel<256, 4, true><<<(Nn + 3) / 4, 256, 0, stream>>>(
        buf2, scales + 3 * (size_t)Nn, b0[0], b0[1], b0[2], a0, h1, Nn);

    // ---- layer 2 ----
    hipMemsetAsync(buf2, 0, 3 * (size_t)Nn * 128 * sizeof(float), stream);
    {
        dim3 g(128 / BN, (Nn + BM - 1) / BM, 3);
        gemm_scaled_kernel<<<g, 256, 0, stream>>>(h1, W1[0], W1[1], W1[2],
                                                  scales, buf1, Nn, 256, 128);
    }
    {
        dim3 g((E + 3) / 4, 1, 3);
        scatter_kernel<128, 2><<<g, 256, 0, stream>>>(buf1, buf2,
            src[0], dst[0], src[1], dst[1], src[2], dst[2], E, Nn);
    }
    attn_kernel<128, 2, false><<<(Nn + 3) / 4, 256, 0, stream>>>(
        buf2, scales + 3 * (size_t)Nn, b1[0], b1[1], b1[2], a1, outH, Nn);

    fc_kernel<<<(Nn + 3) / 4, 256, 0, stream>>>(outH, fcw, fcb, logits, Nn);
}

// Round 2
// 750.140 us; speedup vs baseline: 5.7806x; 5.7806x over previous
//
#include <hip/hip_runtime.h>

#define BM 64
#define BN 64
#define BKK 16

// ---------------- degree counting ----------------
__global__ __launch_bounds__(256)
void count_deg_kernel(const int* __restrict__ s0, const int* __restrict__ d0,
                      const int* __restrict__ s1, const int* __restrict__ d1,
                      const int* __restrict__ s2, const int* __restrict__ d2,
                      int* __restrict__ deg, int E, int Nn)
{
    int z = blockIdx.z;
    const int* sp = (z == 0) ? s0 : ((z == 1) ? s1 : s2);
    const int* dp = (z == 0) ? d0 : ((z == 1) ? d1 : d2);
    int e = blockIdx.x * blockDim.x + threadIdx.x;
    if (e >= E) return;
    atomicAdd(&deg[z * Nn + sp[e]], 1);        // out-degree (src) for type z
    atomicAdd(&deg[(3 + z) * Nn + dp[e]], 1);  // in-degree (dst)
}

__global__ __launch_bounds__(256)
void make_scales_kernel(const int* __restrict__ deg, float* __restrict__ scales, int total)
{
    int i = blockIdx.x * blockDim.x + threadIdx.x;
    if (i >= total) return;
    int dv = deg[i];
    if (dv < 1) dv = 1;
    scales[i] = rsqrtf((float)dv);
}

// ---------------- exclusive scan of in-degrees -> CSR rowptr ----------------
// one wave per edge type; sequential 64-wide chunked scan with carry
__global__ __launch_bounds__(64)
void scan_rowptr_kernel(const int* __restrict__ deg,  // in-deg at (3+z)*Nn
                        int* __restrict__ rowptr,     // [3][Nn+1]
                        int Nn)
{
    const int z = blockIdx.x;
    const int* d = deg + (size_t)(3 + z) * Nn;
    int* rp = rowptr + (size_t)z * (Nn + 1);
    const int lane = threadIdx.x;
    int carry = 0;
    for (int base = 0; base < Nn; base += 64) {
        const int i = base + lane;
        const int v = (i < Nn) ? d[i] : 0;
        int incl = v;
        #pragma unroll
        for (int off = 1; off < 64; off <<= 1) {
            int nv = __shfl_up(incl, off);
            if (lane >= off) incl += nv;
        }
        if (i < Nn) rp[i] = carry + incl - v;  // exclusive
        carry += __shfl(incl, 63);
    }
    if (lane == 0) rp[Nn] = carry;
}

// ---------------- CSR fill (slot via int atomic) ----------------
__global__ __launch_bounds__(256)
void fill_csr_kernel(const int* __restrict__ s0, const int* __restrict__ d0,
                     const int* __restrict__ s1, const int* __restrict__ d1,
                     const int* __restrict__ s2, const int* __restrict__ d2,
                     const int* __restrict__ rowptr,  // [3][Nn+1]
                     int* __restrict__ cursor,        // [3][Nn], zeroed
                     int* __restrict__ csr,           // [3][E] src ids sorted by dst
                     int E, int Nn)
{
    const int z = blockIdx.z;
    const int* sp = (z == 0) ? s0 : ((z == 1) ? s1 : s2);
    const int* dp = (z == 0) ? d0 : ((z == 1) ? d1 : d2);
    int e = blockIdx.x * blockDim.x + threadIdx.x;
    if (e >= E) return;
    const int dn = dp[e];
    const int pos = atomicAdd(&cursor[z * Nn + dn], 1);
    csr[(size_t)z * E + rowptr[(size_t)z * (Nn + 1) + dn] + pos] = sp[e];
}

// ---------------- fp32 tiled GEMM with per-row scale epilogue ----------------
// C[z][r][c] = s_out[z][r] * sum_k A[r][k] * Bz[k][c]
__global__ __launch_bounds__(256)
void gemm_scaled_kernel(const float* __restrict__ A,
                        const float* __restrict__ B0, const float* __restrict__ B1,
                        const float* __restrict__ B2,
                        const float* __restrict__ scales,  // s_out[t*M + r]
                        float* __restrict__ Cbase,
                        int M, int K, int Ncols)
{
    const int z = blockIdx.z;
    const float* B = (z == 0) ? B0 : ((z == 1) ? B1 : B2);
    const float* s = scales + (size_t)z * M;
    float* C = Cbase + (size_t)z * M * Ncols;

    __shared__ float As[BKK][BM + 4];
    __shared__ float Bs[BKK][BN];

    const int tid = threadIdx.x;
    const int tx = tid & 15;
    const int ty = tid >> 4;
    const int row0 = blockIdx.y * BM;
    const int col0 = blockIdx.x * BN;

    const int ar  = tid >> 2;
    const int ac4 = (tid & 3) * 4;
    const int br  = tid >> 4;
    const int bc4 = (tid & 15) * 4;

    float acc[4][4] = {};

    for (int k0 = 0; k0 < K; k0 += BKK) {
        float4 av = make_float4(0.f, 0.f, 0.f, 0.f);
        const int arow = row0 + ar;
        const int kc = k0 + ac4;
        if (arow < M) {
            if (kc + 3 < K) {
                av = *reinterpret_cast<const float4*>(A + (size_t)arow * K + kc);
            } else {
                float t0 = (kc + 0 < K) ? A[(size_t)arow * K + kc + 0] : 0.f;
                float t1 = (kc + 1 < K) ? A[(size_t)arow * K + kc + 1] : 0.f;
                float t2 = (kc + 2 < K) ? A[(size_t)arow * K + kc + 2] : 0.f;
                float t3 = (kc + 3 < K) ? A[(size_t)arow * K + kc + 3] : 0.f;
                av = make_float4(t0, t1, t2, t3);
            }
        }
        As[ac4 + 0][ar] = av.x;
        As[ac4 + 1][ar] = av.y;
        As[ac4 + 2][ar] = av.z;
        As[ac4 + 3][ar] = av.w;

        float4 bv = make_float4(0.f, 0.f, 0.f, 0.f);
        const int brow = k0 + br;
        if (brow < K) {
            bv = *reinterpret_cast<const float4*>(B + (size_t)brow * Ncols + col0 + bc4);
        }
        *reinterpret_cast<float4*>(&Bs[br][bc4]) = bv;

        __syncthreads();

        #pragma unroll
        for (int k = 0; k < BKK; ++k) {
            float4 a4 = *reinterpret_cast<const float4*>(&As[k][ty * 4]);
            float4 b4 = *reinterpret_cast<const float4*>(&Bs[k][tx * 4]);
            float aa[4] = {a4.x, a4.y, a4.z, a4.w};
            float bb[4] = {b4.x, b4.y, b4.z, b4.w};
            #pragma unroll
            for (int i = 0; i < 4; ++i)
                #pragma unroll
                for (int j = 0; j < 4; ++j)
                    acc[i][j] = fmaf(aa[i], bb[j], acc[i][j]);
        }
        __syncthreads();
    }

    #pragma unroll
    for (int i = 0; i < 4; ++i) {
        const int r = row0 + ty * 4 + i;
        if (r < M) {
            const float sc = s[r];
            float4 o = make_float4(acc[i][0] * sc, acc[i][1] * sc,
                                   acc[i][2] * sc, acc[i][3] * sc);
            *reinterpret_cast<float4*>(C + (size_t)r * Ncols + col0 + tx * 4) = o;
        }
    }
}

// ---------------- fused CSR-gather + dual-attention (+ optional FC) ----------------
// agg[t] = sum_{e in CSR_t(n)} pre[t][src_e]   (pre is already s_out-scaled)
// ht[t] = agg[t]*s_in[t][n] + b_t ; sc_t = ht[t].a[:F] + mean.a[F:]
// LeakyReLU(0.2); softmax over t; out = sum_t attn_t*ht[t] (opt LeakyReLU 0.01)
template <int F, int VEC, bool LEAKY01, bool FUSE_FC>
__global__ __launch_bounds__(256)
void gather_attn_kernel(const float* __restrict__ pre,     // [3][Nn][F]
                        const int* __restrict__ rowptr,    // [3][Nn+1]
                        const int* __restrict__ csr,       // [3][E]
                        const float* __restrict__ sin_,    // s_in[t*Nn + n]
                        const float* __restrict__ bb0, const float* __restrict__ bb1,
                        const float* __restrict__ bb2,
                        const float* __restrict__ a,       // [2F]
                        const float* __restrict__ fcw,     // [F][10] (if FUSE_FC)
                        const float* __restrict__ fcb,     // [10]
                        float* __restrict__ out,           // [Nn][F]
                        float* __restrict__ logits,        // [Nn][10]
                        int Nn, int E)
{
    const int wave = blockIdx.x * 4 + (threadIdx.x >> 6);
    const int lane = threadIdx.x & 63;
    if (wave >= Nn) return;
    const int n = wave;
    const size_t NF = (size_t)Nn * F;
    const int fo = lane * VEC;

    float ht[3][VEC];
    float mean[VEC];
    #pragma unroll
    for (int v = 0; v < VEC; ++v) mean[v] = 0.f;

    const float* bptr[3] = {bb0, bb1, bb2};
    #pragma unroll
    for (int t = 0; t < 3; ++t) {
        const int* rp = rowptr + (size_t)t * (Nn + 1);
        const int beg = rp[n];
        const int end = rp[n + 1];
        const int* lst = csr + (size_t)t * E;
        const float* P = pre + t * NF;

        float acc[VEC];
        #pragma unroll
        for (int v = 0; v < VEC; ++v) acc[v] = 0.f;

        for (int j = beg; j < end; ++j) {
            const int s = lst[j];  // uniform across wave
            const float* rowp = P + (size_t)s * F + fo;
            if constexpr (VEC == 4) {
                float4 r4 = *reinterpret_cast<const float4*>(rowp);
                acc[0] += r4.x; acc[1] += r4.y; acc[2] += r4.z; acc[3] += r4.w;
            } else {
                float2 r2 = *reinterpret_cast<const float2*>(rowp);
                acc[0] += r2.x; acc[1] += r2.y;
            }
        }

        const float si = sin_[t * Nn + n];
        const float* bp = bptr[t] + fo;
        #pragma unroll
        for (int v = 0; v < VEC; ++v) {
            const float xv = fmaf(acc[v], si, bp[v]);
            ht[t][v] = xv;
            mean[v] += xv;
        }
    }
    #pragma unroll
    for (int v = 0; v < VEC; ++v) mean[v] *= (1.0f / 3.0f);

    float p0 = 0.f, p1 = 0.f, p2 = 0.f, p3 = 0.f;
    #pragma unroll
    for (int v = 0; v < VEC; ++v) {
        const float aA = a[fo + v];
        const float aB = a[F + fo + v];
        p0 = fmaf(ht[0][v], aA, p0);
        p1 = fmaf(ht[1][v], aA, p1);
        p2 = fmaf(ht[2][v], aA, p2);
        p3 = fmaf(mean[v], aB, p3);
    }
    #pragma unroll
    for (int off = 1; off < 64; off <<= 1) {
        p0 += __shfl_xor(p0, off);
        p1 += __shfl_xor(p1, off);
        p2 += __shfl_xor(p2, off);
        p3 += __shfl_xor(p3, off);
    }
    float sc0 = p0 + p3, sc1 = p1 + p3, sc2 = p2 + p3;
    sc0 = sc0 > 0.f ? sc0 : 0.2f * sc0;
    sc1 = sc1 > 0.f ? sc1 : 0.2f * sc1;
    sc2 = sc2 > 0.f ? sc2 : 0.2f * sc2;
    const float m = fmaxf(sc0, fmaxf(sc1, sc2));
    const float e0 = __expf(sc0 - m);
    const float e1 = __expf(sc1 - m);
    const float e2 = __expf(sc2 - m);
    const float inv = 1.0f / (e0 + e1 + e2);
    const float at0 = e0 * inv, at1 = e1 * inv, at2 = e2 * inv;

    float o[VEC];
    #pragma unroll
    for (int v = 0; v < VEC; ++v) {
        float ov = at0 * ht[0][v] + at1 * ht[1][v] + at2 * ht[2][v];
        if constexpr (LEAKY01) ov = ov > 0.f ? ov : 0.01f * ov;
        o[v] = ov;
    }
    float* op = out + (size_t)n * F + fo;
    #pragma unroll
    for (int v = 0; v < VEC; ++v) op[v] = o[v];

    if constexpr (FUSE_FC) {
        float accc[10];
        #pragma unroll
        for (int c = 0; c < 10; ++c) {
            float s = 0.f;
            #pragma unroll
            for (int v = 0; v < VEC; ++v)
                s = fmaf(o[v], fcw[(fo + v) * 10 + c], s);
            accc[c] = s;
        }
        #pragma unroll
        for (int off = 1; off < 64; off <<= 1) {
            #pragma unroll
            for (int c = 0; c < 10; ++c) accc[c] += __shfl_xor(accc[c], off);
        }
        if (lane == 0) {
            #pragma unroll
            for (int c = 0; c < 10; ++c)
                logits[(size_t)n * 10 + c] = accc[c] + fcb[c];
        }
    }
}

extern "C" void kernel_launch(void* const* d_in, const int* in_sizes, int n_in,
                              void* d_out, int out_size, void* d_ws, size_t ws_size,
                              hipStream_t stream)
{
    const float* x = (const float*)d_in[0];
    const int* src[3] = {(const int*)d_in[1], (const int*)d_in[3], (const int*)d_in[5]};
    const int* dst[3] = {(const int*)d_in[2], (const int*)d_in[4], (const int*)d_in[6]};
    const float* W0[3] = {(const float*)d_in[7],  (const float*)d_in[11], (const float*)d_in[15]};
    const float* b0[3] = {(const float*)d_in[8],  (const float*)d_in[12], (const float*)d_in[16]};
    const float* W1[3] = {(const float*)d_in[9],  (const float*)d_in[13], (const float*)d_in[17]};
    const float* b1[3] = {(const float*)d_in[10], (const float*)d_in[14], (const float*)d_in[18]};
    const float* a0  = (const float*)d_in[19];
    const float* a1  = (const float*)d_in[20];
    const float* fcw = (const float*)d_in[21];
    const float* fcb = (const float*)d_in[22];

    const int Nn = in_sizes[0] / 300;  // 20000
    const int E  = in_sizes[1];        // 320000

    // ---- workspace layout (byte offsets, 16B-aligned blocks) ----
    char* wsb = (char*)d_ws;
    size_t off = 0;
    auto take = [&](size_t bytes) { char* p = wsb + off; off = (off + bytes + 15) & ~(size_t)15; return p; };
    int*   deg    = (int*)take(6 * (size_t)Nn * sizeof(int));          // [6][Nn]
    int*   cursor = (int*)take(3 * (size_t)Nn * sizeof(int));          // [3][Nn]
    int*   rowptr = (int*)take(3 * ((size_t)Nn + 1) * sizeof(int));    // [3][Nn+1]
    int*   csr    = (int*)take(3 * (size_t)E * sizeof(int));           // [3][E]
    float* scales = (float*)take(6 * (size_t)Nn * sizeof(float));      // s_out[3][Nn], s_in[3][Nn]
    float* buf1   = (float*)take(3 * (size_t)Nn * 256 * sizeof(float));
    float* h1     = (float*)take((size_t)Nn * 256 * sizeof(float));

    float* outH   = (float*)d_out;                    // N*128
    float* logits = outH + (size_t)Nn * 128;          // N*10

    hipMemsetAsync(deg, 0, 6 * (size_t)Nn * sizeof(int), stream);
    hipMemsetAsync(cursor, 0, 3 * (size_t)Nn * sizeof(int), stream);

    {
        dim3 g((E + 255) / 256, 1, 3);
        count_deg_kernel<<<g, 256, 0, stream>>>(src[0], dst[0], src[1], dst[1],
                                                src[2], dst[2], deg, E, Nn);
    }
    make_scales_kernel<<<(6 * Nn + 255) / 256, 256, 0, stream>>>(deg, scales, 6 * Nn);
    scan_rowptr_kernel<<<3, 64, 0, stream>>>(deg, rowptr, Nn);
    {
        dim3 g((E + 255) / 256, 1, 3);
        fill_csr_kernel<<<g, 256, 0, stream>>>(src[0], dst[0], src[1], dst[1],
                                               src[2], dst[2], rowptr, cursor, csr, E, Nn);
    }

    // ---- layer 1 ----
    {
        dim3 g(256 / BN, (Nn + BM - 1) / BM, 3);
        gemm_scaled_kernel<<<g, 256, 0, stream>>>(x, W0[0], W0[1], W0[2],
                                                  scales, buf1, Nn, 300, 256);
    }
    gather_attn_kernel<256, 4, true, false><<<(Nn + 3) / 4, 256, 0, stream>>>(
        buf1, rowptr, csr, scales + 3 * (size_t)Nn,
        b0[0], b0[1], b0[2], a0, nullptr, nullptr, h1, nullptr, Nn, E);

    // ---- layer 2 ----
    {
        dim3 g(128 / BN, (Nn + BM - 1) / BM, 3);
        gemm_scaled_kernel<<<g, 256, 0, stream>>>(h1, W1[0], W1[1], W1[2],
                                                  scales, buf1, Nn, 256, 128);
    }
    gather_attn_kernel<128, 2, false, true><<<(Nn + 3) / 4, 256, 0, stream>>>(
        buf1, rowptr, csr, scales + 3 * (size_t)Nn,
        b1[0], b1[1], b1[2], a1, fcw, fcb, outH, logits, Nn, E);
}

// Round 3
// 629.609 us; speedup vs baseline: 6.8872x; 1.1914x over previous
//
#include <hip/hip_runtime.h>

#define BM 64
#define BN 64
#define BKK 16

// ---------------- degree counting ----------------
__global__ __launch_bounds__(256)
void count_deg_kernel(const int* __restrict__ s0, const int* __restrict__ d0,
                      const int* __restrict__ s1, const int* __restrict__ d1,
                      const int* __restrict__ s2, const int* __restrict__ d2,
                      int* __restrict__ deg, int E, int Nn)
{
    int z = blockIdx.z;
    const int* sp = (z == 0) ? s0 : ((z == 1) ? s1 : s2);
    const int* dp = (z == 0) ? d0 : ((z == 1) ? d1 : d2);
    int e = blockIdx.x * blockDim.x + threadIdx.x;
    if (e >= E) return;
    atomicAdd(&deg[z * Nn + sp[e]], 1);        // out-degree (src) for type z
    atomicAdd(&deg[(3 + z) * Nn + dp[e]], 1);  // in-degree (dst)
}

__global__ __launch_bounds__(256)
void make_scales_kernel(const int* __restrict__ deg, float* __restrict__ scales, int total)
{
    int i = blockIdx.x * blockDim.x + threadIdx.x;
    if (i >= total) return;
    int dv = deg[i];
    if (dv < 1) dv = 1;
    scales[i] = rsqrtf((float)dv);
}

// ---------------- exclusive scan of in-degrees -> CSR rowptr ----------------
// one 1024-thread block per edge type: per-thread chunk sum, LDS scan, write
__global__ __launch_bounds__(1024)
void scan_rowptr_kernel(const int* __restrict__ deg,  // in-deg at (3+z)*Nn
                        int* __restrict__ rowptr,     // [3][Nn+1]
                        int Nn)
{
    const int z = blockIdx.x;
    const int* d = deg + (size_t)(3 + z) * Nn;
    int* rp = rowptr + (size_t)z * (Nn + 1);
    const int t = threadIdx.x;
    const int chunk = (Nn + 1023) / 1024;
    const int beg = t * chunk;
    const int end = min(beg + chunk, Nn);

    // 1) per-thread partial sum
    int partial = 0;
    for (int i = beg; i < end; ++i) partial += d[i];

    // 2) block-wide inclusive scan over partials (Hillis-Steele in LDS)
    __shared__ int s[1024];
    s[t] = partial;
    __syncthreads();
    #pragma unroll
    for (int off = 1; off < 1024; off <<= 1) {
        int v = (t >= off) ? s[t - off] : 0;
        __syncthreads();
        s[t] += v;
        __syncthreads();
    }
    const int excl = s[t] - partial;

    // 3) write exclusive prefixes for this chunk
    int run = excl;
    for (int i = beg; i < end; ++i) { rp[i] = run; run += d[i]; }
    if (t == 1023) rp[Nn] = s[1023];
}

// ---------------- CSR fill (slot via int atomic) ----------------
__global__ __launch_bounds__(256)
void fill_csr_kernel(const int* __restrict__ s0, const int* __restrict__ d0,
                     const int* __restrict__ s1, const int* __restrict__ d1,
                     const int* __restrict__ s2, const int* __restrict__ d2,
                     const int* __restrict__ rowptr,  // [3][Nn+1]
                     int* __restrict__ cursor,        // [3][Nn], zeroed
                     int* __restrict__ csr,           // [3][E] src ids sorted by dst
                     int E, int Nn)
{
    const int z = blockIdx.z;
    const int* sp = (z == 0) ? s0 : ((z == 1) ? s1 : s2);
    const int* dp = (z == 0) ? d0 : ((z == 1) ? d1 : d2);
    int e = blockIdx.x * blockDim.x + threadIdx.x;
    if (e >= E) return;
    const int dn = dp[e];
    const int pos = atomicAdd(&cursor[z * Nn + dn], 1);
    csr[(size_t)z * E + rowptr[(size_t)z * (Nn + 1) + dn] + pos] = sp[e];
}

// ---------------- fp32 tiled GEMM with per-row scale epilogue ----------------
// C[z][r][c] = s_out[z][r] * sum_k A[r][k] * Bz[k][c]
__global__ __launch_bounds__(256)
void gemm_scaled_kernel(const float* __restrict__ A,
                        const float* __restrict__ B0, const float* __restrict__ B1,
                        const float* __restrict__ B2,
                        const float* __restrict__ scales,  // s_out[t*M + r]
                        float* __restrict__ Cbase,
                        int M, int K, int Ncols)
{
    const int z = blockIdx.z;
    const float* B = (z == 0) ? B0 : ((z == 1) ? B1 : B2);
    const float* s = scales + (size_t)z * M;
    float* C = Cbase + (size_t)z * M * Ncols;

    __shared__ float As[BKK][BM + 4];
    __shared__ float Bs[BKK][BN];

    const int tid = threadIdx.x;
    const int tx = tid & 15;
    const int ty = tid >> 4;
    const int row0 = blockIdx.y * BM;
    const int col0 = blockIdx.x * BN;

    const int ar  = tid >> 2;
    const int ac4 = (tid & 3) * 4;
    const int br  = tid >> 4;
    const int bc4 = (tid & 15) * 4;

    float acc[4][4] = {};

    for (int k0 = 0; k0 < K; k0 += BKK) {
        float4 av = make_float4(0.f, 0.f, 0.f, 0.f);
        const int arow = row0 + ar;
        const int kc = k0 + ac4;
        if (arow < M) {
            if (kc + 3 < K) {
                av = *reinterpret_cast<const float4*>(A + (size_t)arow * K + kc);
            } else {
                float t0 = (kc + 0 < K) ? A[(size_t)arow * K + kc + 0] : 0.f;
                float t1 = (kc + 1 < K) ? A[(size_t)arow * K + kc + 1] : 0.f;
                float t2 = (kc + 2 < K) ? A[(size_t)arow * K + kc + 2] : 0.f;
                float t3 = (kc + 3 < K) ? A[(size_t)arow * K + kc + 3] : 0.f;
                av = make_float4(t0, t1, t2, t3);
            }
        }
        As[ac4 + 0][ar] = av.x;
        As[ac4 + 1][ar] = av.y;
        As[ac4 + 2][ar] = av.z;
        As[ac4 + 3][ar] = av.w;

        float4 bv = make_float4(0.f, 0.f, 0.f, 0.f);
        const int brow = k0 + br;
        if (brow < K) {
            bv = *reinterpret_cast<const float4*>(B + (size_t)brow * Ncols + col0 + bc4);
        }
        *reinterpret_cast<float4*>(&Bs[br][bc4]) = bv;

        __syncthreads();

        #pragma unroll
        for (int k = 0; k < BKK; ++k) {
            float4 a4 = *reinterpret_cast<const float4*>(&As[k][ty * 4]);
            float4 b4 = *reinterpret_cast<const float4*>(&Bs[k][tx * 4]);
            float aa[4] = {a4.x, a4.y, a4.z, a4.w};
            float bb[4] = {b4.x, b4.y, b4.z, b4.w};
            #pragma unroll
            for (int i = 0; i < 4; ++i)
                #pragma unroll
                for (int j = 0; j < 4; ++j)
                    acc[i][j] = fmaf(aa[i], bb[j], acc[i][j]);
        }
        __syncthreads();
    }

    #pragma unroll
    for (int i = 0; i < 4; ++i) {
        const int r = row0 + ty * 4 + i;
        if (r < M) {
            const float sc = s[r];
            float4 o = make_float4(acc[i][0] * sc, acc[i][1] * sc,
                                   acc[i][2] * sc, acc[i][3] * sc);
            *reinterpret_cast<float4*>(C + (size_t)r * Ncols + col0 + tx * 4) = o;
        }
    }
}

// ---------------- fused CSR-gather + dual-attention (+ optional FC) ----------------
template <int F, int VEC, bool LEAKY01, bool FUSE_FC>
__global__ __launch_bounds__(256)
void gather_attn_kernel(const float* __restrict__ pre,     // [3][Nn][F]
                        const int* __restrict__ rowptr,    // [3][Nn+1]
                        const int* __restrict__ csr,       // [3][E]
                        const float* __restrict__ sin_,    // s_in[t*Nn + n]
                        const float* __restrict__ bb0, const float* __restrict__ bb1,
                        const float* __restrict__ bb2,
                        const float* __restrict__ a,       // [2F]
                        const float* __restrict__ fcw,     // [F][10] (if FUSE_FC)
                        const float* __restrict__ fcb,     // [10]
                        float* __restrict__ out,           // [Nn][F]
                        float* __restrict__ logits,        // [Nn][10]
                        int Nn, int E)
{
    const int wave = blockIdx.x * 4 + (threadIdx.x >> 6);
    const int lane = threadIdx.x & 63;
    if (wave >= Nn) return;
    const int n = wave;
    const size_t NF = (size_t)Nn * F;
    const int fo = lane * VEC;

    float ht[3][VEC];
    float mean[VEC];
    #pragma unroll
    for (int v = 0; v < VEC; ++v) mean[v] = 0.f;

    const float* bptr[3] = {bb0, bb1, bb2};
    #pragma unroll
    for (int t = 0; t < 3; ++t) {
        const int* rp = rowptr + (size_t)t * (Nn + 1);
        const int beg = rp[n];
        const int end = rp[n + 1];
        const int* lst = csr + (size_t)t * E;
        const float* P = pre + t * NF;

        float acc[VEC];
        #pragma unroll
        for (int v = 0; v < VEC; ++v) acc[v] = 0.f;

        for (int j = beg; j < end; ++j) {
            const int s = lst[j];  // uniform across wave
            const float* rowp = P + (size_t)s * F + fo;
            if constexpr (VEC == 4) {
                float4 r4 = *reinterpret_cast<const float4*>(rowp);
                acc[0] += r4.x; acc[1] += r4.y; acc[2] += r4.z; acc[3] += r4.w;
            } else {
                float2 r2 = *reinterpret_cast<const float2*>(rowp);
                acc[0] += r2.x; acc[1] += r2.y;
            }
        }

        const float si = sin_[t * Nn + n];
        const float* bp = bptr[t] + fo;
        #pragma unroll
        for (int v = 0; v < VEC; ++v) {
            const float xv = fmaf(acc[v], si, bp[v]);
            ht[t][v] = xv;
            mean[v] += xv;
        }
    }
    #pragma unroll
    for (int v = 0; v < VEC; ++v) mean[v] *= (1.0f / 3.0f);

    float p0 = 0.f, p1 = 0.f, p2 = 0.f, p3 = 0.f;
    #pragma unroll
    for (int v = 0; v < VEC; ++v) {
        const float aA = a[fo + v];
        const float aB = a[F + fo + v];
        p0 = fmaf(ht[0][v], aA, p0);
        p1 = fmaf(ht[1][v], aA, p1);
        p2 = fmaf(ht[2][v], aA, p2);
        p3 = fmaf(mean[v], aB, p3);
    }
    #pragma unroll
    for (int off = 1; off < 64; off <<= 1) {
        p0 += __shfl_xor(p0, off);
        p1 += __shfl_xor(p1, off);
        p2 += __shfl_xor(p2, off);
        p3 += __shfl_xor(p3, off);
    }
    float sc0 = p0 + p3, sc1 = p1 + p3, sc2 = p2 + p3;
    sc0 = sc0 > 0.f ? sc0 : 0.2f * sc0;
    sc1 = sc1 > 0.f ? sc1 : 0.2f * sc1;
    sc2 = sc2 > 0.f ? sc2 : 0.2f * sc2;
    const float m = fmaxf(sc0, fmaxf(sc1, sc2));
    const float e0 = __expf(sc0 - m);
    const float e1 = __expf(sc1 - m);
    const float e2 = __expf(sc2 - m);
    const float inv = 1.0f / (e0 + e1 + e2);
    const float at0 = e0 * inv, at1 = e1 * inv, at2 = e2 * inv;

    float o[VEC];
    #pragma unroll
    for (int v = 0; v < VEC; ++v) {
        float ov = at0 * ht[0][v] + at1 * ht[1][v] + at2 * ht[2][v];
        if constexpr (LEAKY01) ov = ov > 0.f ? ov : 0.01f * ov;
        o[v] = ov;
    }
    float* op = out + (size_t)n * F + fo;
    #pragma unroll
    for (int v = 0; v < VEC; ++v) op[v] = o[v];

    if constexpr (FUSE_FC) {
        float accc[10];
        #pragma unroll
        for (int c = 0; c < 10; ++c) {
            float s = 0.f;
            #pragma unroll
            for (int v = 0; v < VEC; ++v)
                s = fmaf(o[v], fcw[(fo + v) * 10 + c], s);
            accc[c] = s;
        }
        #pragma unroll
        for (int off = 1; off < 64; off <<= 1) {
            #pragma unroll
            for (int c = 0; c < 10; ++c) accc[c] += __shfl_xor(accc[c], off);
        }
        if (lane == 0) {
            #pragma unroll
            for (int c = 0; c < 10; ++c)
                logits[(size_t)n * 10 + c] = accc[c] + fcb[c];
        }
    }
}

extern "C" void kernel_launch(void* const* d_in, const int* in_sizes, int n_in,
                              void* d_out, int out_size, void* d_ws, size_t ws_size,
                              hipStream_t stream)
{
    const float* x = (const float*)d_in[0];
    const int* src[3] = {(const int*)d_in[1], (const int*)d_in[3], (const int*)d_in[5]};
    const int* dst[3] = {(const int*)d_in[2], (const int*)d_in[4], (const int*)d_in[6]};
    const float* W0[3] = {(const float*)d_in[7],  (const float*)d_in[11], (const float*)d_in[15]};
    const float* b0[3] = {(const float*)d_in[8],  (const float*)d_in[12], (const float*)d_in[16]};
    const float* W1[3] = {(const float*)d_in[9],  (const float*)d_in[13], (const float*)d_in[17]};
    const float* b1[3] = {(const float*)d_in[10], (const float*)d_in[14], (const float*)d_in[18]};
    const float* a0  = (const float*)d_in[19];
    const float* a1  = (const float*)d_in[20];
    const float* fcw = (const float*)d_in[21];
    const float* fcb = (const float*)d_in[22];

    const int Nn = in_sizes[0] / 300;  // 20000
    const int E  = in_sizes[1];        // 320000

    // ---- workspace layout (byte offsets, 16B-aligned blocks) ----
    char* wsb = (char*)d_ws;
    size_t off = 0;
    auto take = [&](size_t bytes) { char* p = wsb + off; off = (off + bytes + 15) & ~(size_t)15; return p; };
    int*   deg    = (int*)take(6 * (size_t)Nn * sizeof(int));          // [6][Nn]
    int*   cursor = (int*)take(3 * (size_t)Nn * sizeof(int));          // [3][Nn]
    int*   rowptr = (int*)take(3 * ((size_t)Nn + 1) * sizeof(int));    // [3][Nn+1]
    int*   csr    = (int*)take(3 * (size_t)E * sizeof(int));           // [3][E]
    float* scales = (float*)take(6 * (size_t)Nn * sizeof(float));      // s_out[3][Nn], s_in[3][Nn]
    float* buf1   = (float*)take(3 * (size_t)Nn * 256 * sizeof(float));
    float* h1     = (float*)take((size_t)Nn * 256 * sizeof(float));

    float* outH   = (float*)d_out;                    // N*128
    float* logits = outH + (size_t)Nn * 128;          // N*10

    hipMemsetAsync(deg, 0, 6 * (size_t)Nn * sizeof(int), stream);
    hipMemsetAsync(cursor, 0, 3 * (size_t)Nn * sizeof(int), stream);

    {
        dim3 g((E + 255) / 256, 1, 3);
        count_deg_kernel<<<g, 256, 0, stream>>>(src[0], dst[0], src[1], dst[1],
                                                src[2], dst[2], deg, E, Nn);
    }
    make_scales_kernel<<<(6 * Nn + 255) / 256, 256, 0, stream>>>(deg, scales, 6 * Nn);
    scan_rowptr_kernel<<<3, 1024, 0, stream>>>(deg, rowptr, Nn);
    {
        dim3 g((E + 255) / 256, 1, 3);
        fill_csr_kernel<<<g, 256, 0, stream>>>(src[0], dst[0], src[1], dst[1],
                                               src[2], dst[2], rowptr, cursor, csr, E, Nn);
    }

    // ---- layer 1 ----
    {
        dim3 g(256 / BN, (Nn + BM - 1) / BM, 3);
        gemm_scaled_kernel<<<g, 256, 0, stream>>>(x, W0[0], W0[1], W0[2],
                                                  scales, buf1, Nn, 300, 256);
    }
    gather_attn_kernel<256, 4, true, false><<<(Nn + 3) / 4, 256, 0, stream>>>(
        buf1, rowptr, csr, scales + 3 * (size_t)Nn,
        b0[0], b0[1], b0[2], a0, nullptr, nullptr, h1, nullptr, Nn, E);

    // ---- layer 2 ----
    {
        dim3 g(128 / BN, (Nn + BM - 1) / BM, 3);
        gemm_scaled_kernel<<<g, 256, 0, stream>>>(h1, W1[0], W1[1], W1[2],
                                                  scales, buf1, Nn, 256, 128);
    }
    gather_attn_kernel<128, 2, false, true><<<(Nn + 3) / 4, 256, 0, stream>>>(
        buf1, rowptr, csr, scales + 3 * (size_t)Nn,
        b1[0], b1[1], b1[2], a1, fcw, fcb, outH, logits, Nn, E);
}

// Round 4
// 535.832 us; speedup vs baseline: 8.0925x; 1.1750x over previous
//
#include <hip/hip_runtime.h>

typedef unsigned short u16;
typedef u16   u16x8  __attribute__((ext_vector_type(8)));
typedef short bf16x8 __attribute__((ext_vector_type(8)));
typedef float f32x4  __attribute__((ext_vector_type(4)));

__device__ inline u16 f2bf_rne(float f) {
    unsigned u = __float_as_uint(f);
    u += 0x7FFFu + ((u >> 16) & 1u);
    return (u16)(u >> 16);
}
__device__ inline float bf2f(u16 h) { return __uint_as_float(((unsigned)h) << 16); }

// ---------------- degree counting ----------------
__global__ __launch_bounds__(256)
void count_deg_kernel(const int* __restrict__ s0, const int* __restrict__ d0,
                      const int* __restrict__ s1, const int* __restrict__ d1,
                      const int* __restrict__ s2, const int* __restrict__ d2,
                      int* __restrict__ deg, int E, int Nn)
{
    int z = blockIdx.z;
    const int* sp = (z == 0) ? s0 : ((z == 1) ? s1 : s2);
    const int* dp = (z == 0) ? d0 : ((z == 1) ? d1 : d2);
    int e = blockIdx.x * blockDim.x + threadIdx.x;
    if (e >= E) return;
    atomicAdd(&deg[z * Nn + sp[e]], 1);
    atomicAdd(&deg[(3 + z) * Nn + dp[e]], 1);
}

__global__ __launch_bounds__(256)
void make_scales_kernel(const int* __restrict__ deg, float* __restrict__ scales, int total)
{
    int i = blockIdx.x * blockDim.x + threadIdx.x;
    if (i >= total) return;
    int dv = deg[i];
    if (dv < 1) dv = 1;
    scales[i] = rsqrtf((float)dv);
}

// ---------------- exclusive scan of in-degrees -> CSR rowptr ----------------
__global__ __launch_bounds__(1024)
void scan_rowptr_kernel(const int* __restrict__ deg,
                        int* __restrict__ rowptr,
                        int Nn)
{
    const int z = blockIdx.x;
    const int* d = deg + (size_t)(3 + z) * Nn;
    int* rp = rowptr + (size_t)z * (Nn + 1);
    const int t = threadIdx.x;
    const int chunk = (Nn + 1023) / 1024;
    const int beg = t * chunk;
    const int end = min(beg + chunk, Nn);

    int partial = 0;
    for (int i = beg; i < end; ++i) partial += d[i];

    __shared__ int s[1024];
    s[t] = partial;
    __syncthreads();
    #pragma unroll
    for (int off = 1; off < 1024; off <<= 1) {
        int v = (t >= off) ? s[t - off] : 0;
        __syncthreads();
        s[t] += v;
        __syncthreads();
    }
    const int excl = s[t] - partial;

    int run = excl;
    for (int i = beg; i < end; ++i) { rp[i] = run; run += d[i]; }
    if (t == 1023) rp[Nn] = s[1023];
}

// ---------------- CSR fill ----------------
__global__ __launch_bounds__(256)
void fill_csr_kernel(const int* __restrict__ s0, const int* __restrict__ d0,
                     const int* __restrict__ s1, const int* __restrict__ d1,
                     const int* __restrict__ s2, const int* __restrict__ d2,
                     const int* __restrict__ rowptr,
                     int* __restrict__ cursor,
                     int* __restrict__ csr,
                     int E, int Nn)
{
    const int z = blockIdx.z;
    const int* sp = (z == 0) ? s0 : ((z == 1) ? s1 : s2);
    const int* dp = (z == 0) ? d0 : ((z == 1) ? d1 : d2);
    int e = blockIdx.x * blockDim.x + threadIdx.x;
    if (e >= E) return;
    const int dn = dp[e];
    const int pos = atomicAdd(&cursor[z * Nn + dn], 1);
    csr[(size_t)z * E + rowptr[(size_t)z * (Nn + 1) + dn] + pos] = sp[e];
}

// ---------------- weight transpose + fp32->bf16 hi/lo split ----------------
// W [K][N] row-major -> Th/Tl [N][Kpad] (zero-padded K tail)
__global__ __launch_bounds__(256)
void wtransp_kernel(const float* __restrict__ W, u16* __restrict__ Th, u16* __restrict__ Tl,
                    int K, int N, int Kpad)
{
    int id = blockIdx.x * 256 + threadIdx.x;
    if (id >= N * Kpad) return;
    int n = id / Kpad, kp = id - n * Kpad;
    float v = (kp < K) ? W[(size_t)kp * N + n] : 0.f;
    u16 hi = f2bf_rne(v);
    u16 lo = f2bf_rne(v - bf2f(hi));
    Th[id] = hi; Tl[id] = lo;
}

// ---------------- split-bf16 MFMA GEMM with per-row scale epilogue ----------------
// C[z][r][c] = s_out[z][r] * sum_k A[r][k]*Bz[k][c],  via Ah*Bh + Ah*Bl + Al*Bh
// A fp32 [M][Kreal]; B pre-transposed hi/lo [Ncols][Kpad] bf16.
// Tile 128x128, BK=32, 4 waves (2x2 of 64x64), mfma_f32_16x16x32_bf16.
template<int KSTEPS>
__global__ __launch_bounds__(256)
void mfma_gemm_kernel(const float* __restrict__ A, int Kreal,
                      const u16* __restrict__ B0h, const u16* __restrict__ B0l,
                      const u16* __restrict__ B1h, const u16* __restrict__ B1l,
                      const u16* __restrict__ B2h, const u16* __restrict__ B2l,
                      const float* __restrict__ scales,
                      float* __restrict__ Cbase, int M, int Ncols)
{
    const int z = blockIdx.z;
    const u16* Bh = (z == 0) ? B0h : ((z == 1) ? B1h : B2h);
    const u16* Bl = (z == 0) ? B0l : ((z == 1) ? B1l : B2l);
    const float* s = scales + (size_t)z * M;
    float* C = Cbase + (size_t)z * M * Ncols;
    const int Kpad = KSTEPS * 32;

    // LDS tiles: [128 rows][32 k] bf16 each, 16B chunks XOR-swizzled by ((row>>1)&3)
    __shared__ u16 Ash[128 * 32], Asl[128 * 32], Bsh[128 * 32], Bsl[128 * 32];

    const int tid  = threadIdx.x;
    const int lane = tid & 63;
    const int wv   = tid >> 6;
    const int wr   = wv >> 1, wc = wv & 1;       // 2x2 wave grid
    const int g    = lane >> 4, lm = lane & 15;
    const int row0 = blockIdx.y * 128, col0 = blockIdx.x * 128;

    // staging mapping: thread -> (row sr, half sh); 16 elements per thread per tile
    const int sr = tid >> 1;
    const int sh = tid & 1;
    const int swz = (sr >> 1) & 3;
    const int c0 = ((sh * 2 + 0) ^ swz) << 4;    // swizzled byte chunk offsets
    const int c1 = ((sh * 2 + 1) ^ swz) << 4;
    const bool arow_ok = (row0 + sr) < M;
    const size_t abase = (size_t)(row0 + sr) * Kreal;
    const size_t bbase = (size_t)(col0 + sr) * Kpad;

    f32x4 acc[4][4];
    #pragma unroll
    for (int i = 0; i < 4; ++i)
        #pragma unroll
        for (int j = 0; j < 4; ++j) acc[i][j] = 0.f;

    for (int st = 0; st < KSTEPS; ++st) {
        const int k0 = st * 32;
        const int kg0 = k0 + sh * 16;

        // ---- A stage: load 16 fp32, split to hi/lo bf16 ----
        u16x8 hh[2], ll[2];
        #pragma unroll
        for (int q = 0; q < 4; ++q) {
            const int kg = kg0 + q * 4;
            float4 v = make_float4(0.f, 0.f, 0.f, 0.f);
            if (arow_ok) {
                if (kg + 3 < Kreal) {
                    v = *reinterpret_cast<const float4*>(A + abase + kg);
                } else {
                    if (kg + 0 < Kreal) v.x = A[abase + kg + 0];
                    if (kg + 1 < Kreal) v.y = A[abase + kg + 1];
                    if (kg + 2 < Kreal) v.z = A[abase + kg + 2];
                    if (kg + 3 < Kreal) v.w = A[abase + kg + 3];
                }
            }
            float fv[4] = {v.x, v.y, v.z, v.w};
            #pragma unroll
            for (int e = 0; e < 4; ++e) {
                u16 hi = f2bf_rne(fv[e]);
                u16 lo = f2bf_rne(fv[e] - bf2f(hi));
                hh[q >> 1][(q & 1) * 4 + e] = hi;
                ll[q >> 1][(q & 1) * 4 + e] = lo;
            }
        }
        {
            char* pAh = (char*)Ash + sr * 64;
            char* pAl = (char*)Asl + sr * 64;
            *(u16x8*)(pAh + c0) = hh[0];
            *(u16x8*)(pAh + c1) = hh[1];
            *(u16x8*)(pAl + c0) = ll[0];
            *(u16x8*)(pAl + c1) = ll[1];
        }
        // ---- B stage: straight copy of pre-converted bf16 ----
        {
            const u16* bph = Bh + bbase + kg0;
            const u16* bpl = Bl + bbase + kg0;
            u16x8 bh0 = *(const u16x8*)(bph);
            u16x8 bh1 = *(const u16x8*)(bph + 8);
            u16x8 bl0 = *(const u16x8*)(bpl);
            u16x8 bl1 = *(const u16x8*)(bpl + 8);
            char* pBh = (char*)Bsh + sr * 64;
            char* pBl = (char*)Bsl + sr * 64;
            *(u16x8*)(pBh + c0) = bh0;
            *(u16x8*)(pBh + c1) = bh1;
            *(u16x8*)(pBl + c0) = bl0;
            *(u16x8*)(pBl + c1) = bl1;
        }

        __syncthreads();

        // ---- fragments + MFMA ----
        bf16x8 afh[4], afl[4], bfh[4], bfl[4];
        #pragma unroll
        for (int mi = 0; mi < 4; ++mi) {
            const int r = wr * 64 + mi * 16 + lm;
            const int byte = r * 64 + ((g ^ ((r >> 1) & 3)) << 4);
            afh[mi] = *(const bf16x8*)((const char*)Ash + byte);
            afl[mi] = *(const bf16x8*)((const char*)Asl + byte);
        }
        #pragma unroll
        for (int ni = 0; ni < 4; ++ni) {
            const int r = wc * 64 + ni * 16 + lm;
            const int byte = r * 64 + ((g ^ ((r >> 1) & 3)) << 4);
            bfh[ni] = *(const bf16x8*)((const char*)Bsh + byte);
            bfl[ni] = *(const bf16x8*)((const char*)Bsl + byte);
        }
        #pragma unroll
        for (int mi = 0; mi < 4; ++mi)
            #pragma unroll
            for (int ni = 0; ni < 4; ++ni) {
                acc[mi][ni] = __builtin_amdgcn_mfma_f32_16x16x32_bf16(afl[mi], bfh[ni], acc[mi][ni], 0, 0, 0);
                acc[mi][ni] = __builtin_amdgcn_mfma_f32_16x16x32_bf16(afh[mi], bfl[ni], acc[mi][ni], 0, 0, 0);
                acc[mi][ni] = __builtin_amdgcn_mfma_f32_16x16x32_bf16(afh[mi], bfh[ni], acc[mi][ni], 0, 0, 0);
            }

        __syncthreads();
    }

    // ---- epilogue: scale by s_out[row], store fp32 ----
    #pragma unroll
    for (int mi = 0; mi < 4; ++mi) {
        #pragma unroll
        for (int reg = 0; reg < 4; ++reg) {
            const int r = row0 + wr * 64 + mi * 16 + g * 4 + reg;
            if (r < M) {
                const float sc = s[r];
                #pragma unroll
                for (int ni = 0; ni < 4; ++ni) {
                    C[(size_t)r * Ncols + col0 + wc * 64 + ni * 16 + lm] = acc[mi][ni][reg] * sc;
                }
            }
        }
    }
}

// ---------------- fused CSR-gather + dual-attention (+ optional FC) ----------------
template <int F, int VEC, bool LEAKY01, bool FUSE_FC>
__global__ __launch_bounds__(256)
void gather_attn_kernel(const float* __restrict__ pre,
                        const int* __restrict__ rowptr,
                        const int* __restrict__ csr,
                        const float* __restrict__ sin_,
                        const float* __restrict__ bb0, const float* __restrict__ bb1,
                        const float* __restrict__ bb2,
                        const float* __restrict__ a,
                        const float* __restrict__ fcw,
                        const float* __restrict__ fcb,
                        float* __restrict__ out,
                        float* __restrict__ logits,
                        int Nn, int E)
{
    const int wave = blockIdx.x * 4 + (threadIdx.x >> 6);
    const int lane = threadIdx.x & 63;
    if (wave >= Nn) return;
    const int n = wave;
    const size_t NF = (size_t)Nn * F;
    const int fo = lane * VEC;

    float ht[3][VEC];
    float mean[VEC];
    #pragma unroll
    for (int v = 0; v < VEC; ++v) mean[v] = 0.f;

    const float* bptr[3] = {bb0, bb1, bb2};
    #pragma unroll
    for (int t = 0; t < 3; ++t) {
        const int* rp = rowptr + (size_t)t * (Nn + 1);
        const int beg = rp[n];
        const int end = rp[n + 1];
        const int* lst = csr + (size_t)t * E;
        const float* P = pre + t * NF;

        float acc[VEC];
        #pragma unroll
        for (int v = 0; v < VEC; ++v) acc[v] = 0.f;

        for (int j = beg; j < end; ++j) {
            const int s = lst[j];
            const float* rowp = P + (size_t)s * F + fo;
            if constexpr (VEC == 4) {
                float4 r4 = *reinterpret_cast<const float4*>(rowp);
                acc[0] += r4.x; acc[1] += r4.y; acc[2] += r4.z; acc[3] += r4.w;
            } else {
                float2 r2 = *reinterpret_cast<const float2*>(rowp);
                acc[0] += r2.x; acc[1] += r2.y;
            }
        }

        const float si = sin_[t * Nn + n];
        const float* bp = bptr[t] + fo;
        #pragma unroll
        for (int v = 0; v < VEC; ++v) {
            const float xv = fmaf(acc[v], si, bp[v]);
            ht[t][v] = xv;
            mean[v] += xv;
        }
    }
    #pragma unroll
    for (int v = 0; v < VEC; ++v) mean[v] *= (1.0f / 3.0f);

    float p0 = 0.f, p1 = 0.f, p2 = 0.f, p3 = 0.f;
    #pragma unroll
    for (int v = 0; v < VEC; ++v) {
        const float aA = a[fo + v];
        const float aB = a[F + fo + v];
        p0 = fmaf(ht[0][v], aA, p0);
        p1 = fmaf(ht[1][v], aA, p1);
        p2 = fmaf(ht[2][v], aA, p2);
        p3 = fmaf(mean[v], aB, p3);
    }
    #pragma unroll
    for (int off = 1; off < 64; off <<= 1) {
        p0 += __shfl_xor(p0, off);
        p1 += __shfl_xor(p1, off);
        p2 += __shfl_xor(p2, off);
        p3 += __shfl_xor(p3, off);
    }
    float sc0 = p0 + p3, sc1 = p1 + p3, sc2 = p2 + p3;
    sc0 = sc0 > 0.f ? sc0 : 0.2f * sc0;
    sc1 = sc1 > 0.f ? sc1 : 0.2f * sc1;
    sc2 = sc2 > 0.f ? sc2 : 0.2f * sc2;
    const float m = fmaxf(sc0, fmaxf(sc1, sc2));
    const float e0 = __expf(sc0 - m);
    const float e1 = __expf(sc1 - m);
    const float e2 = __expf(sc2 - m);
    const float inv = 1.0f / (e0 + e1 + e2);
    const float at0 = e0 * inv, at1 = e1 * inv, at2 = e2 * inv;

    float o[VEC];
    #pragma unroll
    for (int v = 0; v < VEC; ++v) {
        float ov = at0 * ht[0][v] + at1 * ht[1][v] + at2 * ht[2][v];
        if constexpr (LEAKY01) ov = ov > 0.f ? ov : 0.01f * ov;
        o[v] = ov;
    }
    float* op = out + (size_t)n * F + fo;
    #pragma unroll
    for (int v = 0; v < VEC; ++v) op[v] = o[v];

    if constexpr (FUSE_FC) {
        float accc[10];
        #pragma unroll
        for (int c = 0; c < 10; ++c) {
            float s = 0.f;
            #pragma unroll
            for (int v = 0; v < VEC; ++v)
                s = fmaf(o[v], fcw[(fo + v) * 10 + c], s);
            accc[c] = s;
        }
        #pragma unroll
        for (int off = 1; off < 64; off <<= 1) {
            #pragma unroll
            for (int c = 0; c < 10; ++c) accc[c] += __shfl_xor(accc[c], off);
        }
        if (lane == 0) {
            #pragma unroll
            for (int c = 0; c < 10; ++c)
                logits[(size_t)n * 10 + c] = accc[c] + fcb[c];
        }
    }
}

extern "C" void kernel_launch(void* const* d_in, const int* in_sizes, int n_in,
                              void* d_out, int out_size, void* d_ws, size_t ws_size,
                              hipStream_t stream)
{
    const float* x = (const float*)d_in[0];
    const int* src[3] = {(const int*)d_in[1], (const int*)d_in[3], (const int*)d_in[5]};
    const int* dst[3] = {(const int*)d_in[2], (const int*)d_in[4], (const int*)d_in[6]};
    const float* W0[3] = {(const float*)d_in[7],  (const float*)d_in[11], (const float*)d_in[15]};
    const float* b0[3] = {(const float*)d_in[8],  (const float*)d_in[12], (const float*)d_in[16]};
    const float* W1[3] = {(const float*)d_in[9],  (const float*)d_in[13], (const float*)d_in[17]};
    const float* b1[3] = {(const float*)d_in[10], (const float*)d_in[14], (const float*)d_in[18]};
    const float* a0  = (const float*)d_in[19];
    const float* a1  = (const float*)d_in[20];
    const float* fcw = (const float*)d_in[21];
    const float* fcb = (const float*)d_in[22];

    const int Nn = in_sizes[0] / 300;  // 20000
    const int E  = in_sizes[1];        // 320000
    const int K1 = 300, K1p = 320, F1 = 256;
    const int K2 = 256, K2p = 256, F2 = 128;

    // ---- workspace layout ----
    char* wsb = (char*)d_ws;
    size_t off = 0;
    auto take = [&](size_t bytes) { char* p = wsb + off; off = (off + bytes + 15) & ~(size_t)15; return p; };
    int*   deg    = (int*)take(6 * (size_t)Nn * sizeof(int));
    int*   cursor = (int*)take(3 * (size_t)Nn * sizeof(int));
    int*   rowptr = (int*)take(3 * ((size_t)Nn + 1) * sizeof(int));
    int*   csr    = (int*)take(3 * (size_t)E * sizeof(int));
    float* scales = (float*)take(6 * (size_t)Nn * sizeof(float));
    float* buf1   = (float*)take(3 * (size_t)Nn * 256 * sizeof(float));
    float* h1     = (float*)take((size_t)Nn * 256 * sizeof(float));
    u16*   wt1h   = (u16*)take(3 * (size_t)F1 * K1p * sizeof(u16));
    u16*   wt1l   = (u16*)take(3 * (size_t)F1 * K1p * sizeof(u16));
    u16*   wt2h   = (u16*)take(3 * (size_t)F2 * K2p * sizeof(u16));
    u16*   wt2l   = (u16*)take(3 * (size_t)F2 * K2p * sizeof(u16));

    float* outH   = (float*)d_out;
    float* logits = outH + (size_t)Nn * 128;

    hipMemsetAsync(deg, 0, 6 * (size_t)Nn * sizeof(int), stream);
    hipMemsetAsync(cursor, 0, 3 * (size_t)Nn * sizeof(int), stream);

    {
        dim3 g((E + 255) / 256, 1, 3);
        count_deg_kernel<<<g, 256, 0, stream>>>(src[0], dst[0], src[1], dst[1],
                                                src[2], dst[2], deg, E, Nn);
    }
    make_scales_kernel<<<(6 * Nn + 255) / 256, 256, 0, stream>>>(deg, scales, 6 * Nn);
    scan_rowptr_kernel<<<3, 1024, 0, stream>>>(deg, rowptr, Nn);
    {
        dim3 g((E + 255) / 256, 1, 3);
        fill_csr_kernel<<<g, 256, 0, stream>>>(src[0], dst[0], src[1], dst[1],
                                               src[2], dst[2], rowptr, cursor, csr, E, Nn);
    }

    // ---- weight transpose/convert ----
    for (int t = 0; t < 3; ++t) {
        wtransp_kernel<<<(F1 * K1p + 255) / 256, 256, 0, stream>>>(
            W0[t], wt1h + (size_t)t * F1 * K1p, wt1l + (size_t)t * F1 * K1p, K1, F1, K1p);
        wtransp_kernel<<<(F2 * K2p + 255) / 256, 256, 0, stream>>>(
            W1[t], wt2h + (size_t)t * F2 * K2p, wt2l + (size_t)t * F2 * K2p, K2, F2, K2p);
    }

    // ---- layer 1: C = s_out * (x @ W0) ----
    {
        dim3 g(F1 / 128, (Nn + 127) / 128, 3);
        mfma_gemm_kernel<10><<<g, 256, 0, stream>>>(
            x, K1,
            wt1h + 0 * (size_t)F1 * K1p, wt1l + 0 * (size_t)F1 * K1p,
            wt1h + 1 * (size_t)F1 * K1p, wt1l + 1 * (size_t)F1 * K1p,
            wt1h + 2 * (size_t)F1 * K1p, wt1l + 2 * (size_t)F1 * K1p,
            scales, buf1, Nn, F1);
    }
    gather_attn_kernel<256, 4, true, false><<<(Nn + 3) / 4, 256, 0, stream>>>(
        buf1, rowptr, csr, scales + 3 * (size_t)Nn,
        b0[0], b0[1], b0[2], a0, nullptr, nullptr, h1, nullptr, Nn, E);

    // ---- layer 2: C = s_out * (h1 @ W1) ----
    {
        dim3 g(F2 / 128, (Nn + 127) / 128, 3);
        mfma_gemm_kernel<8><<<g, 256, 0, stream>>>(
            h1, K2,
            wt2h + 0 * (size_t)F2 * K2p, wt2l + 0 * (size_t)F2 * K2p,
            wt2h + 1 * (size_t)F2 * K2p, wt2l + 1 * (size_t)F2 * K2p,
            wt2h + 2 * (size_t)F2 * K2p, wt2l + 2 * (size_t)F2 * K2p,
            scales, buf1, Nn, F2);
    }
    gather_attn_kernel<128, 2, false, true><<<(Nn + 3) / 4, 256, 0, stream>>>(
        buf1, rowptr, csr, scales + 3 * (size_t)Nn,
        b1[0], b1[1], b1[2], a1, fcw, fcb, outH, logits, Nn, E);
}

// Round 5
// 483.870 us; speedup vs baseline: 8.9616x; 1.1074x over previous
//
#include <hip/hip_runtime.h>

typedef unsigned short u16;
typedef u16   u16x8  __attribute__((ext_vector_type(8)));
typedef short bf16x8 __attribute__((ext_vector_type(8)));
typedef float f32x4  __attribute__((ext_vector_type(4)));

__device__ inline u16 f2bf_rne(float f) {
    unsigned u = __float_as_uint(f);
    u += 0x7FFFu + ((u >> 16) & 1u);
    return (u16)(u >> 16);
}
__device__ inline float bf2f(u16 h) { return __uint_as_float(((unsigned)h) << 16); }

// ---------------- degree counting ----------------
__global__ __launch_bounds__(256)
void count_deg_kernel(const int* __restrict__ s0, const int* __restrict__ d0,
                      const int* __restrict__ s1, const int* __restrict__ d1,
                      const int* __restrict__ s2, const int* __restrict__ d2,
                      int* __restrict__ deg, int E, int Nn)
{
    int z = blockIdx.z;
    const int* sp = (z == 0) ? s0 : ((z == 1) ? s1 : s2);
    const int* dp = (z == 0) ? d0 : ((z == 1) ? d1 : d2);
    int e = blockIdx.x * blockDim.x + threadIdx.x;
    if (e >= E) return;
    atomicAdd(&deg[z * Nn + sp[e]], 1);
    atomicAdd(&deg[(3 + z) * Nn + dp[e]], 1);
}

__global__ __launch_bounds__(256)
void make_scales_kernel(const int* __restrict__ deg, float* __restrict__ scales, int total)
{
    int i = blockIdx.x * blockDim.x + threadIdx.x;
    if (i >= total) return;
    int dv = deg[i];
    if (dv < 1) dv = 1;
    scales[i] = rsqrtf((float)dv);
}

// ---------------- exclusive scan of in-degrees -> CSR rowptr ----------------
__global__ __launch_bounds__(1024)
void scan_rowptr_kernel(const int* __restrict__ deg,
                        int* __restrict__ rowptr,
                        int Nn)
{
    const int z = blockIdx.x;
    const int* d = deg + (size_t)(3 + z) * Nn;
    int* rp = rowptr + (size_t)z * (Nn + 1);
    const int t = threadIdx.x;
    const int chunk = (Nn + 1023) / 1024;
    const int beg = t * chunk;
    const int end = min(beg + chunk, Nn);

    int partial = 0;
    for (int i = beg; i < end; ++i) partial += d[i];

    __shared__ int s[1024];
    s[t] = partial;
    __syncthreads();
    #pragma unroll
    for (int off = 1; off < 1024; off <<= 1) {
        int v = (t >= off) ? s[t - off] : 0;
        __syncthreads();
        s[t] += v;
        __syncthreads();
    }
    const int excl = s[t] - partial;

    int run = excl;
    for (int i = beg; i < end; ++i) { rp[i] = run; run += d[i]; }
    if (t == 1023) rp[Nn] = s[1023];
}

// ---------------- CSR fill ----------------
__global__ __launch_bounds__(256)
void fill_csr_kernel(const int* __restrict__ s0, const int* __restrict__ d0,
                     const int* __restrict__ s1, const int* __restrict__ d1,
                     const int* __restrict__ s2, const int* __restrict__ d2,
                     const int* __restrict__ rowptr,
                     int* __restrict__ cursor,
                     int* __restrict__ csr,
                     int E, int Nn)
{
    const int z = blockIdx.z;
    const int* sp = (z == 0) ? s0 : ((z == 1) ? s1 : s2);
    const int* dp = (z == 0) ? d0 : ((z == 1) ? d1 : d2);
    int e = blockIdx.x * blockDim.x + threadIdx.x;
    if (e >= E) return;
    const int dn = dp[e];
    const int pos = atomicAdd(&cursor[z * Nn + dn], 1);
    csr[(size_t)z * E + rowptr[(size_t)z * (Nn + 1) + dn] + pos] = sp[e];
}

// ---------------- weight transpose + fp32->bf16 hi/lo split (3 types in z) ----------------
__global__ __launch_bounds__(256)
void wtransp3_kernel(const float* __restrict__ Wa, const float* __restrict__ Wb,
                     const float* __restrict__ Wc,
                     u16* __restrict__ Th, u16* __restrict__ Tl,
                     int K, int N, int Kpad)
{
    const int z = blockIdx.z;
    const float* W = (z == 0) ? Wa : ((z == 1) ? Wb : Wc);
    u16* th = Th + (size_t)z * N * Kpad;
    u16* tl = Tl + (size_t)z * N * Kpad;
    int id = blockIdx.x * 256 + threadIdx.x;
    if (id >= N * Kpad) return;
    int n = id / Kpad, kp = id - n * Kpad;
    float v = (kp < K) ? W[(size_t)kp * N + n] : 0.f;
    u16 hi = f2bf_rne(v);
    u16 lo = f2bf_rne(v - bf2f(hi));
    th[id] = hi; tl[id] = lo;
}

// ---------------- split-bf16 MFMA GEMM with per-row scale epilogue ----------------
template<int KSTEPS>
__global__ __launch_bounds__(256)
void mfma_gemm_kernel(const float* __restrict__ A, int Kreal,
                      const u16* __restrict__ B0h, const u16* __restrict__ B0l,
                      const u16* __restrict__ B1h, const u16* __restrict__ B1l,
                      const u16* __restrict__ B2h, const u16* __restrict__ B2l,
                      const float* __restrict__ scales,
                      float* __restrict__ Cbase, int M, int Ncols)
{
    const int z = blockIdx.z;
    const u16* Bh = (z == 0) ? B0h : ((z == 1) ? B1h : B2h);
    const u16* Bl = (z == 0) ? B0l : ((z == 1) ? B1l : B2l);
    const float* s = scales + (size_t)z * M;
    float* C = Cbase + (size_t)z * M * Ncols;
    const int Kpad = KSTEPS * 32;

    __shared__ u16 Ash[128 * 32], Asl[128 * 32], Bsh[128 * 32], Bsl[128 * 32];

    const int tid  = threadIdx.x;
    const int lane = tid & 63;
    const int wv   = tid >> 6;
    const int wr   = wv >> 1, wc = wv & 1;
    const int g    = lane >> 4, lm = lane & 15;
    const int row0 = blockIdx.y * 128, col0 = blockIdx.x * 128;

    const int sr = tid >> 1;
    const int sh = tid & 1;
    const int swz = (sr >> 1) & 3;
    const int c0 = ((sh * 2 + 0) ^ swz) << 4;
    const int c1 = ((sh * 2 + 1) ^ swz) << 4;
    const bool arow_ok = (row0 + sr) < M;
    const size_t abase = (size_t)(row0 + sr) * Kreal;
    const size_t bbase = (size_t)(col0 + sr) * Kpad;

    f32x4 acc[4][4];
    #pragma unroll
    for (int i = 0; i < 4; ++i)
        #pragma unroll
        for (int j = 0; j < 4; ++j) acc[i][j] = 0.f;

    for (int st = 0; st < KSTEPS; ++st) {
        const int kg0 = st * 32 + sh * 16;

        u16x8 hh[2], ll[2];
        #pragma unroll
        for (int q = 0; q < 4; ++q) {
            const int kg = kg0 + q * 4;
            float4 v = make_float4(0.f, 0.f, 0.f, 0.f);
            if (arow_ok) {
                if (kg + 3 < Kreal) {
                    v = *reinterpret_cast<const float4*>(A + abase + kg);
                } else {
                    if (kg + 0 < Kreal) v.x = A[abase + kg + 0];
                    if (kg + 1 < Kreal) v.y = A[abase + kg + 1];
                    if (kg + 2 < Kreal) v.z = A[abase + kg + 2];
                    if (kg + 3 < Kreal) v.w = A[abase + kg + 3];
                }
            }
            float fv[4] = {v.x, v.y, v.z, v.w};
            #pragma unroll
            for (int e = 0; e < 4; ++e) {
                u16 hi = f2bf_rne(fv[e]);
                u16 lo = f2bf_rne(fv[e] - bf2f(hi));
                hh[q >> 1][(q & 1) * 4 + e] = hi;
                ll[q >> 1][(q & 1) * 4 + e] = lo;
            }
        }
        {
            char* pAh = (char*)Ash + sr * 64;
            char* pAl = (char*)Asl + sr * 64;
            *(u16x8*)(pAh + c0) = hh[0];
            *(u16x8*)(pAh + c1) = hh[1];
            *(u16x8*)(pAl + c0) = ll[0];
            *(u16x8*)(pAl + c1) = ll[1];
        }
        {
            const u16* bph = Bh + bbase + kg0;
            const u16* bpl = Bl + bbase + kg0;
            u16x8 bh0 = *(const u16x8*)(bph);
            u16x8 bh1 = *(const u16x8*)(bph + 8);
            u16x8 bl0 = *(const u16x8*)(bpl);
            u16x8 bl1 = *(const u16x8*)(bpl + 8);
            char* pBh = (char*)Bsh + sr * 64;
            char* pBl = (char*)Bsl + sr * 64;
            *(u16x8*)(pBh + c0) = bh0;
            *(u16x8*)(pBh + c1) = bh1;
            *(u16x8*)(pBl + c0) = bl0;
            *(u16x8*)(pBl + c1) = bl1;
        }

        __syncthreads();

        bf16x8 afh[4], afl[4], bfh[4], bfl[4];
        #pragma unroll
        for (int mi = 0; mi < 4; ++mi) {
            const int r = wr * 64 + mi * 16 + lm;
            const int byte = r * 64 + ((g ^ ((r >> 1) & 3)) << 4);
            afh[mi] = *(const bf16x8*)((const char*)Ash + byte);
            afl[mi] = *(const bf16x8*)((const char*)Asl + byte);
        }
        #pragma unroll
        for (int ni = 0; ni < 4; ++ni) {
            const int r = wc * 64 + ni * 16 + lm;
            const int byte = r * 64 + ((g ^ ((r >> 1) & 3)) << 4);
            bfh[ni] = *(const bf16x8*)((const char*)Bsh + byte);
            bfl[ni] = *(const bf16x8*)((const char*)Bsl + byte);
        }
        #pragma unroll
        for (int mi = 0; mi < 4; ++mi)
            #pragma unroll
            for (int ni = 0; ni < 4; ++ni) {
                acc[mi][ni] = __builtin_amdgcn_mfma_f32_16x16x32_bf16(afl[mi], bfh[ni], acc[mi][ni], 0, 0, 0);
                acc[mi][ni] = __builtin_amdgcn_mfma_f32_16x16x32_bf16(afh[mi], bfl[ni], acc[mi][ni], 0, 0, 0);
                acc[mi][ni] = __builtin_amdgcn_mfma_f32_16x16x32_bf16(afh[mi], bfh[ni], acc[mi][ni], 0, 0, 0);
            }

        __syncthreads();
    }

    #pragma unroll
    for (int mi = 0; mi < 4; ++mi) {
        #pragma unroll
        for (int reg = 0; reg < 4; ++reg) {
            const int r = row0 + wr * 64 + mi * 16 + g * 4 + reg;
            if (r < M) {
                const float sc = s[r];
                #pragma unroll
                for (int ni = 0; ni < 4; ++ni) {
                    C[(size_t)r * Ncols + col0 + wc * 64 + ni * 16 + lm] = acc[mi][ni][reg] * sc;
                }
            }
        }
    }
}

// ---------------- fused CSR-gather + dual-attention (+ optional FC) ----------------
// gather: indices preloaded lane-parallel, row-gathers 4-deep unrolled for MLP
template <int F, int VEC, bool LEAKY01, bool FUSE_FC>
__global__ __launch_bounds__(256)
void gather_attn_kernel(const float* __restrict__ pre,
                        const int* __restrict__ rowptr,
                        const int* __restrict__ csr,
                        const float* __restrict__ sin_,
                        const float* __restrict__ bb0, const float* __restrict__ bb1,
                        const float* __restrict__ bb2,
                        const float* __restrict__ a,
                        const float* __restrict__ fcw,
                        const float* __restrict__ fcb,
                        float* __restrict__ out,
                        float* __restrict__ logits,
                        int Nn, int E)
{
    const int wave = blockIdx.x * 4 + (threadIdx.x >> 6);
    const int lane = threadIdx.x & 63;
    if (wave >= Nn) return;
    const int n = wave;
    const size_t NF = (size_t)Nn * F;
    const int fo = lane * VEC;

    float ht[3][VEC];
    float mean[VEC];
    #pragma unroll
    for (int v = 0; v < VEC; ++v) mean[v] = 0.f;

    const float* bptr[3] = {bb0, bb1, bb2};
    #pragma unroll
    for (int t = 0; t < 3; ++t) {
        const int* rp = rowptr + (size_t)t * (Nn + 1);
        const int beg = rp[n];
        const int end = rp[n + 1];
        const int* lst = csr + (size_t)t * E;
        const float* P = pre + t * NF;

        float a0v[VEC], a1v[VEC], a2v[VEC], a3v[VEC];
        #pragma unroll
        for (int v = 0; v < VEC; ++v) { a0v[v] = 0.f; a1v[v] = 0.f; a2v[v] = 0.f; a3v[v] = 0.f; }

        for (int j = beg; j < end; j += 64) {
            const int cnt = min(64, end - j);
            // coalesced lane-parallel index preload
            int myIdx = (lane < cnt) ? lst[j + lane] : 0;
            int k = 0;
            for (; k + 4 <= cnt; k += 4) {
                const int s0 = __shfl(myIdx, k + 0);
                const int s1 = __shfl(myIdx, k + 1);
                const int s2 = __shfl(myIdx, k + 2);
                const int s3 = __shfl(myIdx, k + 3);
                if constexpr (VEC == 4) {
                    float4 r0 = *reinterpret_cast<const float4*>(P + (size_t)s0 * F + fo);
                    float4 r1 = *reinterpret_cast<const float4*>(P + (size_t)s1 * F + fo);
                    float4 r2 = *reinterpret_cast<const float4*>(P + (size_t)s2 * F + fo);
                    float4 r3 = *reinterpret_cast<const float4*>(P + (size_t)s3 * F + fo);
                    a0v[0] += r0.x; a0v[1] += r0.y; a0v[2] += r0.z; a0v[3] += r0.w;
                    a1v[0] += r1.x; a1v[1] += r1.y; a1v[2] += r1.z; a1v[3] += r1.w;
                    a2v[0] += r2.x; a2v[1] += r2.y; a2v[2] += r2.z; a2v[3] += r2.w;
                    a3v[0] += r3.x; a3v[1] += r3.y; a3v[2] += r3.z; a3v[3] += r3.w;
                } else {
                    float2 r0 = *reinterpret_cast<const float2*>(P + (size_t)s0 * F + fo);
                    float2 r1 = *reinterpret_cast<const float2*>(P + (size_t)s1 * F + fo);
                    float2 r2 = *reinterpret_cast<const float2*>(P + (size_t)s2 * F + fo);
                    float2 r3 = *reinterpret_cast<const float2*>(P + (size_t)s3 * F + fo);
                    a0v[0] += r0.x; a0v[1] += r0.y;
                    a1v[0] += r1.x; a1v[1] += r1.y;
                    a2v[0] += r2.x; a2v[1] += r2.y;
                    a3v[0] += r3.x; a3v[1] += r3.y;
                }
            }
            for (; k < cnt; ++k) {
                const int sI = __shfl(myIdx, k);
                const float* rowp = P + (size_t)sI * F + fo;
                if constexpr (VEC == 4) {
                    float4 r4 = *reinterpret_cast<const float4*>(rowp);
                    a0v[0] += r4.x; a0v[1] += r4.y; a0v[2] += r4.z; a0v[3] += r4.w;
                } else {
                    float2 r2 = *reinterpret_cast<const float2*>(rowp);
                    a0v[0] += r2.x; a0v[1] += r2.y;
                }
            }
        }

        const float si = sin_[t * Nn + n];
        const float* bp = bptr[t] + fo;
        #pragma unroll
        for (int v = 0; v < VEC; ++v) {
            const float sum = (a0v[v] + a1v[v]) + (a2v[v] + a3v[v]);
            const float xv = fmaf(sum, si, bp[v]);
            ht[t][v] = xv;
            mean[v] += xv;
        }
    }
    #pragma unroll
    for (int v = 0; v < VEC; ++v) mean[v] *= (1.0f / 3.0f);

    float p0 = 0.f, p1 = 0.f, p2 = 0.f, p3 = 0.f;
    #pragma unroll
    for (int v = 0; v < VEC; ++v) {
        const float aA = a[fo + v];
        const float aB = a[F + fo + v];
        p0 = fmaf(ht[0][v], aA, p0);
        p1 = fmaf(ht[1][v], aA, p1);
        p2 = fmaf(ht[2][v], aA, p2);
        p3 = fmaf(mean[v], aB, p3);
    }
    #pragma unroll
    for (int off = 1; off < 64; off <<= 1) {
        p0 += __shfl_xor(p0, off);
        p1 += __shfl_xor(p1, off);
        p2 += __shfl_xor(p2, off);
        p3 += __shfl_xor(p3, off);
    }
    float sc0 = p0 + p3, sc1 = p1 + p3, sc2 = p2 + p3;
    sc0 = sc0 > 0.f ? sc0 : 0.2f * sc0;
    sc1 = sc1 > 0.f ? sc1 : 0.2f * sc1;
    sc2 = sc2 > 0.f ? sc2 : 0.2f * sc2;
    const float m = fmaxf(sc0, fmaxf(sc1, sc2));
    const float e0 = __expf(sc0 - m);
    const float e1 = __expf(sc1 - m);
    const float e2 = __expf(sc2 - m);
    const float inv = 1.0f / (e0 + e1 + e2);
    const float at0 = e0 * inv, at1 = e1 * inv, at2 = e2 * inv;

    float o[VEC];
    #pragma unroll
    for (int v = 0; v < VEC; ++v) {
        float ov = at0 * ht[0][v] + at1 * ht[1][v] + at2 * ht[2][v];
        if constexpr (LEAKY01) ov = ov > 0.f ? ov : 0.01f * ov;
        o[v] = ov;
    }
    float* op = out + (size_t)n * F + fo;
    #pragma unroll
    for (int v = 0; v < VEC; ++v) op[v] = o[v];

    if constexpr (FUSE_FC) {
        float accc[10];
        #pragma unroll
        for (int c = 0; c < 10; ++c) {
            float s = 0.f;
            #pragma unroll
            for (int v = 0; v < VEC; ++v)
                s = fmaf(o[v], fcw[(fo + v) * 10 + c], s);
            accc[c] = s;
        }
        #pragma unroll
        for (int off = 1; off < 64; off <<= 1) {
            #pragma unroll
            for (int c = 0; c < 10; ++c) accc[c] += __shfl_xor(accc[c], off);
        }
        if (lane == 0) {
            #pragma unroll
            for (int c = 0; c < 10; ++c)
                logits[(size_t)n * 10 + c] = accc[c] + fcb[c];
        }
    }
}

extern "C" void kernel_launch(void* const* d_in, const int* in_sizes, int n_in,
                              void* d_out, int out_size, void* d_ws, size_t ws_size,
                              hipStream_t stream)
{
    const float* x = (const float*)d_in[0];
    const int* src[3] = {(const int*)d_in[1], (const int*)d_in[3], (const int*)d_in[5]};
    const int* dst[3] = {(const int*)d_in[2], (const int*)d_in[4], (const int*)d_in[6]};
    const float* W0[3] = {(const float*)d_in[7],  (const float*)d_in[11], (const float*)d_in[15]};
    const float* b0[3] = {(const float*)d_in[8],  (const float*)d_in[12], (const float*)d_in[16]};
    const float* W1[3] = {(const float*)d_in[9],  (const float*)d_in[13], (const float*)d_in[17]};
    const float* b1[3] = {(const float*)d_in[10], (const float*)d_in[14], (const float*)d_in[18]};
    const float* a0  = (const float*)d_in[19];
    const float* a1  = (const float*)d_in[20];
    const float* fcw = (const float*)d_in[21];
    const float* fcb = (const float*)d_in[22];

    const int Nn = in_sizes[0] / 300;  // 20000
    const int E  = in_sizes[1];        // 320000
    const int K1 = 300, K1p = 320, F1 = 256;
    const int K2 = 256, K2p = 256, F2 = 128;

    // ---- workspace layout ----
    char* wsb = (char*)d_ws;
    size_t off = 0;
    auto take = [&](size_t bytes) { char* p = wsb + off; off = (off + bytes + 15) & ~(size_t)15; return p; };
    int*   deg    = (int*)take(6 * (size_t)Nn * sizeof(int));
    int*   cursor = (int*)take(3 * (size_t)Nn * sizeof(int));
    int*   rowptr = (int*)take(3 * ((size_t)Nn + 1) * sizeof(int));
    int*   csr    = (int*)take(3 * (size_t)E * sizeof(int));
    float* scales = (float*)take(6 * (size_t)Nn * sizeof(float));
    float* buf1   = (float*)take(3 * (size_t)Nn * 256 * sizeof(float));
    float* h1     = (float*)take((size_t)Nn * 256 * sizeof(float));
    u16*   wt1h   = (u16*)take(3 * (size_t)F1 * K1p * sizeof(u16));
    u16*   wt1l   = (u16*)take(3 * (size_t)F1 * K1p * sizeof(u16));
    u16*   wt2h   = (u16*)take(3 * (size_t)F2 * K2p * sizeof(u16));
    u16*   wt2l   = (u16*)take(3 * (size_t)F2 * K2p * sizeof(u16));

    float* outH   = (float*)d_out;
    float* logits = outH + (size_t)Nn * 128;

    hipMemsetAsync(deg, 0, 6 * (size_t)Nn * sizeof(int), stream);
    hipMemsetAsync(cursor, 0, 3 * (size_t)Nn * sizeof(int), stream);

    {
        dim3 g((E + 255) / 256, 1, 3);
        count_deg_kernel<<<g, 256, 0, stream>>>(src[0], dst[0], src[1], dst[1],
                                                src[2], dst[2], deg, E, Nn);
    }
    make_scales_kernel<<<(6 * Nn + 255) / 256, 256, 0, stream>>>(deg, scales, 6 * Nn);
    scan_rowptr_kernel<<<3, 1024, 0, stream>>>(deg, rowptr, Nn);
    {
        dim3 g((E + 255) / 256, 1, 3);
        fill_csr_kernel<<<g, 256, 0, stream>>>(src[0], dst[0], src[1], dst[1],
                                               src[2], dst[2], rowptr, cursor, csr, E, Nn);
    }

    // ---- weight transpose/convert (one launch per layer, types in z) ----
    {
        dim3 g1((F1 * K1p + 255) / 256, 1, 3);
        wtransp3_kernel<<<g1, 256, 0, stream>>>(W0[0], W0[1], W0[2], wt1h, wt1l, K1, F1, K1p);
        dim3 g2((F2 * K2p + 255) / 256, 1, 3);
        wtransp3_kernel<<<g2, 256, 0, stream>>>(W1[0], W1[1], W1[2], wt2h, wt2l, K2, F2, K2p);
    }

    // ---- layer 1 ----
    {
        dim3 g(F1 / 128, (Nn + 127) / 128, 3);
        mfma_gemm_kernel<10><<<g, 256, 0, stream>>>(
            x, K1,
            wt1h + 0 * (size_t)F1 * K1p, wt1l + 0 * (size_t)F1 * K1p,
            wt1h + 1 * (size_t)F1 * K1p, wt1l + 1 * (size_t)F1 * K1p,
            wt1h + 2 * (size_t)F1 * K1p, wt1l + 2 * (size_t)F1 * K1p,
            scales, buf1, Nn, F1);
    }
    gather_attn_kernel<256, 4, true, false><<<(Nn + 3) / 4, 256, 0, stream>>>(
        buf1, rowptr, csr, scales + 3 * (size_t)Nn,
        b0[0], b0[1], b0[2], a0, nullptr, nullptr, h1, nullptr, Nn, E);

    // ---- layer 2 ----
    {
        dim3 g(F2 / 128, (Nn + 127) / 128, 3);
        mfma_gemm_kernel<8><<<g, 256, 0, stream>>>(
            h1, K2,
            wt2h + 0 * (size_t)F2 * K2p, wt2l + 0 * (size_t)F2 * K2p,
            wt2h + 1 * (size_t)F2 * K2p, wt2l + 1 * (size_t)F2 * K2p,
            wt2h + 2 * (size_t)F2 * K2p, wt2l + 2 * (size_t)F2 * K2p,
            scales, buf1, Nn, F2);
    }
    gather_attn_kernel<128, 2, false, true><<<(Nn + 3) / 4, 256, 0, stream>>>(
        buf1, rowptr, csr, scales + 3 * (size_t)Nn,
        b1[0], b1[1], b1[2], a1, fcw, fcb, outH, logits, Nn, E);
}